// Round 1
// baseline (396.974 us; speedup 1.0000x reference)
//
#include <hip/hip_runtime.h>
#include <math.h>

// NormalLoss: for each template vertex (M=6890), take the K=15 scan points
// (N=20000) with LARGEST distance (torch.topk largest=True faithfulness),
// among them pick min-angle normal match, mse = mean ||sv[sel]-tv||.
//
// Design: wave-cooperative top-K (entries one-per-lane in lanes 0..K-1),
// ballot-serialized rare inserts, LDS-staged float4 scan points shared by
// 4 waves x V=2 vertices per wave.

constexpr int K = 15;
constexpr int CHUNK = 2048;   // float4 points staged per block iteration (32 KB)
constexpr int WAVES = 4;      // waves per block
constexpr int V = 2;          // template vertices per wave

__global__ void zero_kernel(float* out) { out[0] = 0.0f; }

__global__ void pack_kernel(const float* __restrict__ sv, float4* __restrict__ dst, int N) {
    int n = blockIdx.x * blockDim.x + threadIdx.x;
    if (n < N) dst[n] = make_float4(sv[3*n+0], sv[3*n+1], sv[3*n+2], 0.0f);
}

template<bool PACKED>
__global__ __launch_bounds__(WAVES * 64) void knn_loss_kernel(
    const float*  __restrict__ sv,   // [N,3]
    const float4* __restrict__ sv4,  // [N] packed (PACKED only)
    const float*  __restrict__ tv,   // [M,3]
    const float*  __restrict__ sn,   // [N,3] scan normals
    const float*  __restrict__ tn,   // [M,3] template normals
    float* __restrict__ out, int N, int M, float invM)
{
    __shared__ float4 pts[CHUNK];

    const int lane      = threadIdx.x & 63;
    const int waveInBlk = threadIdx.x >> 6;
    const int waveId    = blockIdx.x * WAVES + waveInBlk;

    // Per-wave vertices
    int  m[V];
    bool vvalid[V];
    float tvx[V], tvy[V], tvz[V];
#pragma unroll
    for (int v = 0; v < V; ++v) {
        int mm = waveId * V + v;
        vvalid[v] = (mm < M);
        m[v] = vvalid[v] ? mm : 0;
        tvx[v] = tv[3*m[v]+0];
        tvy[v] = tv[3*m[v]+1];
        tvz[v] = tv[3*m[v]+2];
    }

    // Wave-cooperative top-K: lanes 0..K-1 hold one entry each.
    // Ordering: "better" = larger d2, ties -> lower index (jax top_k stable).
    // Sentinels: empty = (-1, INT_MAX) (any d2>=0 beats it);
    // lanes >= K hold +huge so the 16-lane argmin never picks them.
    float eV[V]; int eI[V]; float thr[V];
#pragma unroll
    for (int v = 0; v < V; ++v) {
        eV[v]  = (lane < K) ? -1.0f : 3.0e38f;
        eI[v]  = 0x7FFFFFFF;
        thr[v] = -1.0f;   // lazy lower bound on current K-th largest
    }

    for (int base = 0; base < N; base += CHUNK) {
        int cnt = min(CHUNK, N - base);
        __syncthreads();
        for (int t = threadIdx.x; t < cnt; t += WAVES * 64) {
            if (PACKED) {
                pts[t] = sv4[base + t];
            } else {
                int g = base + t;
                pts[t] = make_float4(sv[3*g+0], sv[3*g+1], sv[3*g+2], 0.0f);
            }
        }
        __syncthreads();

        // Uniform control flow across the wave (lanes past cnt masked via 'has')
        for (int ib = 0; ib < cnt; ib += 64) {
            int  i   = ib + lane;
            bool has = (i < cnt);
            float4 p = pts[has ? i : 0];
#pragma unroll
            for (int v = 0; v < V; ++v) {
                float dx = p.x - tvx[v];
                float dy = p.y - tvy[v];
                float dz = p.z - tvz[v];
                float d2 = fmaf(dx, dx, fmaf(dy, dy, dz * dz));
                unsigned long long mb = __ballot(has && (d2 > thr[v]));
                while (mb) {
                    int src = __ffsll(mb) - 1;
                    mb &= mb - 1;
                    float cv = __shfl(d2, src);
                    int   ci = base + ib + src;
                    // Find worst entry (min d2, ties -> larger idx) over lanes 0..15.
                    float wv_ = eV[v]; int wi_ = eI[v]; int wl_ = lane;
#pragma unroll
                    for (int s = 1; s < 16; s <<= 1) {
                        float ov = __shfl_xor(wv_, s);
                        int   oi = __shfl_xor(wi_, s);
                        int   ol = __shfl_xor(wl_, s);
                        bool worse = (ov < wv_) || (ov == wv_ && oi > wi_);
                        if (worse) { wv_ = ov; wi_ = oi; wl_ = ol; }
                    }
                    float wv = __shfl(wv_, 0);   // true min over entries
                    int   wl = __shfl(wl_, 0);
                    thr[v] = wv;                 // tighten lazy threshold
                    // Candidates arrive in increasing index order, so equal-d2
                    // never replaces (lower index kept) -> strict >.
                    if (cv > wv) {
                        if (lane == wl && lane < K) { eV[v] = cv; eI[v] = ci; }
                    }
                }
            }
        }
    }

    // Epilogue per vertex: angle = acos(clip(dot(sn[idx], tn[m]))), argmin with
    // tie-break by top-k rank (= first occurrence in knn order).
#pragma unroll
    for (int v = 0; v < V; ++v) {
        float tnx = tn[3*m[v]+0], tny = tn[3*m[v]+1], tnz = tn[3*m[v]+2];

        // rank of my entry = #entries better than mine
        int rank = 0;
#pragma unroll
        for (int f = 0; f < K; ++f) {
            float fv = __shfl(eV[v], f);
            int   fi = __shfl(eI[v], f);
            bool better = (fv > eV[v]) || (fv == eV[v] && fi < eI[v]);
            rank += better ? 1 : 0;
        }

        float ang  = 1.0e30f;
        int myIdx  = eI[v];
        if (lane < K) {
            int i3 = 3 * myIdx;
            float dot = sn[i3+0]*tnx + sn[i3+1]*tny + sn[i3+2]*tnz;
            dot = fminf(1.0f, fmaxf(-1.0f, dot));
            ang = acosf(dot);
        }

        float ba = ang; int br = rank; int bi = myIdx;
#pragma unroll
        for (int s = 1; s < 64; s <<= 1) {
            float oa  = __shfl_xor(ba, s);
            int   orr = __shfl_xor(br, s);
            int   oi  = __shfl_xor(bi, s);
            bool take = (oa < ba) || (oa == ba && orr < br);
            if (take) { ba = oa; br = orr; bi = oi; }
        }

        if (vvalid[v] && lane == 0) {
            int i3 = 3 * bi;
            float dx = sv[i3+0] - tvx[v];
            float dy = sv[i3+1] - tvy[v];
            float dz = sv[i3+2] - tvz[v];
            float nrm = sqrtf(dx*dx + dy*dy + dz*dz);
            atomicAdd(out, nrm * invM);
        }
    }
}

extern "C" void kernel_launch(void* const* d_in, const int* in_sizes, int n_in,
                              void* d_out, int out_size, void* d_ws, size_t ws_size,
                              hipStream_t stream) {
    const float* sv = (const float*)d_in[0];   // scan_vertices  [1,N,3]
    const float* tv = (const float*)d_in[1];   // template_vertices [1,M,3]
    const float* sn = (const float*)d_in[2];   // scan_normals   [N,3]
    const float* tn = (const float*)d_in[3];   // template_normals [M,3]
    // d_in[4] = K_knn (always 15; compile-time constant here)

    int N = in_sizes[0] / 3;
    int M = in_sizes[1] / 3;
    float* out = (float*)d_out;
    float invM = 1.0f / (float)M;

    zero_kernel<<<1, 1, 0, stream>>>(out);

    int grid = (M + WAVES * V - 1) / (WAVES * V);
    if (ws_size >= (size_t)N * sizeof(float4)) {
        float4* sv4 = (float4*)d_ws;
        pack_kernel<<<(N + 255) / 256, 256, 0, stream>>>(sv, sv4, N);
        knn_loss_kernel<true><<<grid, WAVES * 64, 0, stream>>>(
            sv, sv4, tv, sn, tn, out, N, M, invM);
    } else {
        knn_loss_kernel<false><<<grid, WAVES * 64, 0, stream>>>(
            sv, nullptr, tv, sn, tn, out, N, M, invM);
    }
}

// Round 2
// 108.286 us; speedup vs baseline: 3.6660x; 3.6660x over previous
//
#include <hip/hip_runtime.h>
#include <math.h>

// NormalLoss: for each template vertex (M=6890), take the K=15 scan points
// (N=20000) with LARGEST distance, among them pick the min-angle normal
// match, loss = mean ||sv[sel]-tv||.
//
// Round-2 design:
//  * prep kernel (1 workgroup): bucket-sort scan points by |p|^2 descending
//    into d_ws as (x,y,z,bitcast(origIdx)) float4, plus exact per-64-block
//    suffix-max of |p|. Sort quality only affects speed; correctness is exact.
//  * main kernel: one wave per vertex. d <= |p|+|tv| => break the scan when
//    (suffixmax|p| + |tv|)^2 < thr (15th-largest d^2 so far). Expected scanned
//    prefix ~100-500 points instead of 20000.
//  * top-K kept sorted across lanes 0..14 (desc d2, asc idx on ties):
//    bootstrap = 64-lane bitonic sort of first block; inserts =
//    ballot+popcount+shfl_up. All tie-breaks explicit on (d2, origIdx) to
//    match jax top_k + argmin-first-occurrence semantics exactly.

constexpr int K = 15;
constexpr int NBUCK = 256;
constexpr int WAVES = 4;     // waves (=vertices) per block in main kernel
constexpr int MAXNB = 1024;  // max N/64 blocks supported by prep LDS (N<=65536)

__device__ __forceinline__ int bucket_of(float k2) {
    int b = (int)(k2 * 8.0f);           // 0.125-wide buckets over |p|^2 in [0,32)
    b = b > (NBUCK - 1) ? (NBUCK - 1) : b;
    return (NBUCK - 1) - b;             // bucket 0 = largest |p|
}

__global__ void zero_out_kernel(float* out) { out[0] = 0.0f; }

__global__ __launch_bounds__(1024) void prep_kernel(
    const float* __restrict__ sv,   // [N,3]
    float4*      __restrict__ sorted, // [N] out: (x,y,z,bitcast(idx)) desc-|p| order
    float*       __restrict__ smax,   // [nb] out: suffix max of |p| per 64-block
    float*       __restrict__ out,    // zeroed here
    int N, int nb)
{
    __shared__ int      hist[NBUCK];
    __shared__ int      cursor[NBUCK];
    __shared__ unsigned bmax[MAXNB];

    int t = threadIdx.x;
    if (t == 0) out[0] = 0.0f;
    if (t < NBUCK) hist[t] = 0;
    for (int j = t; j < nb; j += 1024) bmax[j] = 0u;
    __syncthreads();

    // histogram of |p|^2 buckets
    for (int i = t; i < N; i += 1024) {
        float x = sv[3*i], y = sv[3*i+1], z = sv[3*i+2];
        atomicAdd(&hist[bucket_of(x*x + y*y + z*z)], 1);
    }
    __syncthreads();

    // Kogge-Stone inclusive scan over hist -> cursor, then shift to exclusive
    if (t < NBUCK) cursor[t] = hist[t];
    __syncthreads();
    for (int d = 1; d < NBUCK; d <<= 1) {
        int v = 0;
        if (t < NBUCK && t >= d) v = cursor[t - d];
        __syncthreads();
        if (t < NBUCK && t >= d) cursor[t] += v;
        __syncthreads();
    }
    int myexc = 0;
    if (t < NBUCK) myexc = (t == 0) ? 0 : cursor[t - 1];
    __syncthreads();
    if (t < NBUCK) cursor[t] = myexc;
    __syncthreads();

    // scatter into bucket-sorted order; track per-64-block max |p|
    for (int i = t; i < N; i += 1024) {
        float x = sv[3*i], y = sv[3*i+1], z = sv[3*i+2];
        float k2 = x*x + y*y + z*z;
        int pos = atomicAdd(&cursor[bucket_of(k2)], 1);
        sorted[pos] = make_float4(x, y, z, __int_as_float(i));
        atomicMax(&bmax[pos >> 6], __float_as_uint(sqrtf(k2))); // >=0: uint order == float order
    }
    __syncthreads();

    // suffix max over bmax -> smax (wave 0 only)
    if (t < 64) {
        int lane = t;
        float running = 0.0f;
        int nchunk = (nb + 63) / 64;
        for (int c = nchunk - 1; c >= 0; --c) {
            int j = c * 64 + lane;
            float v = (j < nb) ? __uint_as_float(bmax[j]) : 0.0f;
#pragma unroll
            for (int d = 1; d < 64; d <<= 1) {
                float o = __shfl_down(v, d);
                if (lane + d < 64) v = fmaxf(v, o);
            }
            v = fmaxf(v, running);       // include chunks to the right
            if (j < nb) smax[j] = v;
            running = __shfl(v, 0);
        }
    }
}

template<bool SORTED>
__global__ __launch_bounds__(WAVES * 64) void knn_loss_kernel(
    const float4* __restrict__ pts,   // sorted points (SORTED only)
    const float*  __restrict__ smax,  // suffix max |p| per block (SORTED only)
    const float*  __restrict__ sv,    // [N,3] original scan vertices
    const float*  __restrict__ tv,    // [M,3]
    const float*  __restrict__ sn,    // [N,3]
    const float*  __restrict__ tn,    // [M,3]
    float* __restrict__ out, int N, int M, float invM)
{
    __shared__ float bsum[WAVES];
    const int lane = threadIdx.x & 63;
    const int w    = threadIdx.x >> 6;
    const int m    = blockIdx.x * WAVES + w;
    const bool valid = (m < M);

    float contrib = 0.0f;
    if (valid) {
        const float tvx = tv[3*m], tvy = tv[3*m+1], tvz = tv[3*m+2];
        const float tlen = sqrtf(tvx*tvx + tvy*tvy + tvz*tvz);

        // ---- bootstrap: bitonic-sort first 64 points desc by (d2, -idx) ----
        float v; int idx;
        {
            float px, py, pz;
            if (SORTED) {
                float4 q = pts[lane];
                px = q.x; py = q.y; pz = q.z; idx = __float_as_int(q.w);
            } else {
                px = sv[3*lane]; py = sv[3*lane+1]; pz = sv[3*lane+2]; idx = lane;
            }
            float dx = px - tvx, dy = py - tvy, dz = pz - tvz;
            v = fmaf(dx, dx, fmaf(dy, dy, dz * dz));
        }
#pragma unroll
        for (int k = 2; k <= 64; k <<= 1) {
#pragma unroll
            for (int j = k >> 1; j > 0; j >>= 1) {
                float ov = __shfl_xor(v, j);
                int   oi = __shfl_xor(idx, j);
                bool up    = ((lane & k) == 0);   // descending segment
                bool lower = ((lane & j) == 0);
                bool mine  = (v > ov) || (v == ov && idx < oi); // total order
                bool keep  = lower ? (up ? mine : !mine) : (up ? !mine : mine);
                if (!keep) { v = ov; idx = oi; }
            }
        }
        // lanes 0..K-1 now hold the exact top-K of the first 64 (sorted desc)
        float eV = (lane < K) ? v : -1.0f;
        int   eI = idx;
        float thr = __shfl(v, K - 1);   // current 15th-largest d2

        // ---- main scan ----
        for (int ib = 64; ib < N; ib += 64) {
            if (SORTED) {
                float bnd = smax[ib >> 6] + tlen;      // upper bound on remaining d
                if (bnd * bnd * 1.00001f < thr) break; // margin covers fp rounding
            }
            int  i   = ib + lane;
            bool has = (i < N);
            float d2; int oi2;
            if (SORTED) {
                float4 q = pts[has ? i : 0];
                float dx = q.x - tvx, dy = q.y - tvy, dz = q.z - tvz;
                d2 = fmaf(dx, dx, fmaf(dy, dy, dz * dz));
                oi2 = __float_as_int(q.w);
            } else {
                int g = has ? i : 0;
                float dx = sv[3*g] - tvx, dy = sv[3*g+1] - tvy, dz = sv[3*g+2] - tvz;
                d2 = fmaf(dx, dx, fmaf(dy, dy, dz * dz));
                oi2 = i;
            }
            // >= : an equal-d2 candidate with lower original idx must displace
            unsigned long long mb = __ballot(has && (d2 >= thr));
            if (mb) {
                do {
                    int src = __ffsll(mb) - 1;
                    mb &= mb - 1;
                    float cv = __shfl(d2, src);
                    int   ci = __shfl(oi2, src);
                    // position = #entries strictly better than candidate
                    unsigned long long bb =
                        __ballot((eV > cv) || (eV == cv && eI < ci)) & 0x7FFFull;
                    int p = __popcll(bb);
                    if (p < K) {   // wave-uniform
                        float uv = __shfl_up(eV, 1);
                        int   ui = __shfl_up(eI, 1);
                        if (lane < K) {
                            if (lane == p)      { eV = cv; eI = ci; }
                            else if (lane > p)  { eV = uv; eI = ui; }
                        }
                    }
                } while (mb);
                thr = __shfl(eV, K - 1);
            }
        }

        // ---- epilogue: argmin angle, tie-break by top-k rank (= lane) ----
        const float tnx = tn[3*m], tny = tn[3*m+1], tnz = tn[3*m+2];
        float ang = 3.0e38f;
        int myI = eI;
        if (lane < K) {
            float dot = sn[3*myI]*tnx + sn[3*myI+1]*tny + sn[3*myI+2]*tnz;
            dot = fminf(1.0f, fmaxf(-1.0f, dot));
            ang = acosf(dot) * 57.29577951308232f;   // degrees, matches jnp
        }
        float ba = ang; int br = lane; int bi = myI;
#pragma unroll
        for (int s = 1; s < 64; s <<= 1) {
            float oa  = __shfl_xor(ba, s);
            int   orr = __shfl_xor(br, s);
            int   oi  = __shfl_xor(bi, s);
            bool take = (oa < ba) || (oa == ba && orr < br);
            if (take) { ba = oa; br = orr; bi = oi; }
        }
        if (lane == 0) {
            float dx = sv[3*bi]   - tvx;
            float dy = sv[3*bi+1] - tvy;
            float dz = sv[3*bi+2] - tvz;
            contrib = sqrtf(dx*dx + dy*dy + dz*dz) * invM;
        }
    }

    if (lane == 0) bsum[w] = contrib;
    __syncthreads();
    if (threadIdx.x == 0) {
        float s = 0.0f;
#pragma unroll
        for (int i = 0; i < WAVES; ++i) s += bsum[i];
        atomicAdd(out, s);
    }
}

extern "C" void kernel_launch(void* const* d_in, const int* in_sizes, int n_in,
                              void* d_out, int out_size, void* d_ws, size_t ws_size,
                              hipStream_t stream) {
    const float* sv = (const float*)d_in[0];   // scan_vertices   [1,N,3]
    const float* tv = (const float*)d_in[1];   // template_vertices [1,M,3]
    const float* sn = (const float*)d_in[2];   // scan_normals    [N,3]
    const float* tn = (const float*)d_in[3];   // template_normals [M,3]
    // d_in[4] = K_knn (fixed 15, compile-time)

    int N = in_sizes[0] / 3;
    int M = in_sizes[1] / 3;
    int nb = (N + 63) / 64;
    float* out = (float*)d_out;
    float invM = 1.0f / (float)M;
    int grid = (M + WAVES - 1) / WAVES;

    size_t need = (size_t)N * sizeof(float4) + (size_t)nb * sizeof(float);
    if (ws_size >= need && nb <= MAXNB) {
        float4* sorted = (float4*)d_ws;
        float*  smax   = (float*)((char*)d_ws + (size_t)N * sizeof(float4));
        prep_kernel<<<1, 1024, 0, stream>>>(sv, sorted, smax, out, N, nb);
        knn_loss_kernel<true><<<grid, WAVES * 64, 0, stream>>>(
            sorted, smax, sv, tv, sn, tn, out, N, M, invM);
    } else {
        zero_out_kernel<<<1, 1, 0, stream>>>(out);
        knn_loss_kernel<false><<<grid, WAVES * 64, 0, stream>>>(
            nullptr, nullptr, sv, tv, sn, tn, out, N, M, invM);
    }
}